// Round 1
// 246.653 us; speedup vs baseline: 1.0669x; 1.0669x over previous
//
#include <hip/hip_runtime.h>
#include <hip/hip_bf16.h>
#include <hip/hip_fp16.h>
#include <math.h>

#define N_NODES 50000
#define N_EDGES 600000
#define D_IN    44

// ---------------- bf16 helpers (bit ops, RNE pack) ----------------

__device__ __forceinline__ unsigned pack_bf2(float a, float b) {
    unsigned ua = __float_as_uint(a);
    ua = (ua + 0x7fffu + ((ua >> 16) & 1u)) >> 16;
    unsigned ub = __float_as_uint(b);
    ub = (ub + 0x7fffu + ((ub >> 16) & 1u)) & 0xffff0000u;
    return ua | ub;
}

#define BL(u) __uint_as_float((u) << 16)
#define BH(u) __uint_as_float((u) & 0xffff0000u)

// ---------------- CSR build ----------------

// packx also zeroes degc (merged k_zero: N << N*22 so grid covers both)
__global__ void k_packx(const float* __restrict__ x, unsigned* __restrict__ xh,
                        int npairs, int* __restrict__ degc, int n) {
    int i = blockIdx.x * blockDim.x + threadIdx.x;
    if (i < npairs) {
        float2 v = ((const float2*)x)[i];
        xh[i] = pack_bf2(v.x, v.y);
    }
    if (i < n) degc[i] = 0;
}

__global__ void k_count(const int* __restrict__ dst, int* degc, int e) {
    int i = blockIdx.x * blockDim.x + threadIdx.x;
    if (i < e) atomicAdd(&degc[dst[i]], 1);
}

__global__ void k_blocksum(const int* __restrict__ degc, int* __restrict__ bsum, int n) {
    int i = blockIdx.x * 256 + threadIdx.x;
    int v = (i < n) ? degc[i] : 0;
    #pragma unroll
    for (int off = 32; off > 0; off >>= 1) v += __shfl_down(v, off, 64);
    __shared__ int ws[4];
    if ((threadIdx.x & 63) == 0) ws[threadIdx.x >> 6] = v;
    __syncthreads();
    if (threadIdx.x == 0) bsum[blockIdx.x] = ws[0] + ws[1] + ws[2] + ws[3];
}

// rowptr now re-scans bsum locally per block (merged k_scanbsum; nb<=256,
// the redundant 256-wide scan is ~200 cycles/block -- cheaper than a launch)
__global__ void k_rowptr(const int* __restrict__ degc, const int* __restrict__ bsum,
                         int* __restrict__ row_ptr, int* __restrict__ cursor,
                         float* __restrict__ dinv, int n, int nb) {
    __shared__ int sb[256];
    __shared__ int s[256];
    int t = threadIdx.x;

    int bv = (t < nb) ? bsum[t] : 0;
    sb[t] = bv;
    __syncthreads();
    #pragma unroll
    for (int off = 1; off < 256; off <<= 1) {
        int u = (t >= off) ? sb[t - off] : 0;
        __syncthreads();
        sb[t] += u;
        __syncthreads();
    }
    int prefix = (blockIdx.x == 0) ? 0 : sb[blockIdx.x - 1];

    int i = blockIdx.x * 256 + t;
    int d = (i < n) ? degc[i] : 0;
    s[t] = d;
    __syncthreads();
    #pragma unroll
    for (int off = 1; off < 256; off <<= 1) {
        int u = (t >= off) ? s[t - off] : 0;
        __syncthreads();
        s[t] += u;
        __syncthreads();
    }
    int ex = s[t] - d + prefix;
    if (i < n) {
        row_ptr[i] = ex;
        cursor[i]  = ex;
        dinv[i]    = rsqrtf(1.0f + (float)d);
        if (i == n - 1) row_ptr[n] = ex + d;
    }
}

// 4-byte CSR entry: src (16 bits, N<65536) | fp16 weight << 16
__global__ void k_fill(const int* __restrict__ src, const int* __restrict__ dst,
                       const float* __restrict__ dinv, int* cursor,
                       unsigned* __restrict__ csr_ew, int e) {
    int i = blockIdx.x * blockDim.x + threadIdx.x;
    if (i < e) {
        int s = src[i], d = dst[i];
        int p = atomicAdd(&cursor[d], 1);
        __half h = __float2half(dinv[s] * dinv[d]);
        csr_ew[p] = (unsigned)s | ((unsigned)__half_as_ushort(h) << 16);
    }
}

// ---------------- 8-deep predicated bf16 gather macros ----------------
// uint2 variant (k_agg1, 44-dim rows = 11 x 8B)

#define AGG_BODY(T2, W4, g, j, acc)                                             \
    {                                                                           \
        int lo = row_ptr[g], hi = row_ptr[(g) + 1];                             \
        for (int k = lo; k < hi; k += 8) {                                      \
            unsigned e0 = csr_ew[min(k + 0, hi - 1)];                           \
            unsigned e1 = csr_ew[min(k + 1, hi - 1)];                           \
            unsigned e2 = csr_ew[min(k + 2, hi - 1)];                           \
            unsigned e3 = csr_ew[min(k + 3, hi - 1)];                           \
            unsigned e4 = csr_ew[min(k + 4, hi - 1)];                           \
            unsigned e5 = csr_ew[min(k + 5, hi - 1)];                           \
            unsigned e6 = csr_ew[min(k + 6, hi - 1)];                           \
            unsigned e7 = csr_ew[min(k + 7, hi - 1)];                           \
            float w0 = __half2float(__ushort_as_half((unsigned short)(e0 >> 16)));                     \
            float w1 = (k + 1 < hi) ? __half2float(__ushort_as_half((unsigned short)(e1 >> 16))) : 0.0f;\
            float w2 = (k + 2 < hi) ? __half2float(__ushort_as_half((unsigned short)(e2 >> 16))) : 0.0f;\
            float w3 = (k + 3 < hi) ? __half2float(__ushort_as_half((unsigned short)(e3 >> 16))) : 0.0f;\
            float w4 = (k + 4 < hi) ? __half2float(__ushort_as_half((unsigned short)(e4 >> 16))) : 0.0f;\
            float w5 = (k + 5 < hi) ? __half2float(__ushort_as_half((unsigned short)(e5 >> 16))) : 0.0f;\
            float w6 = (k + 6 < hi) ? __half2float(__ushort_as_half((unsigned short)(e6 >> 16))) : 0.0f;\
            float w7 = (k + 7 < hi) ? __half2float(__ushort_as_half((unsigned short)(e7 >> 16))) : 0.0f;\
            uint2 t0 = T2[(size_t)(e0 & 0xffffu) * (W4) + (j)];                 \
            uint2 t1 = T2[(size_t)(e1 & 0xffffu) * (W4) + (j)];                 \
            uint2 t2 = T2[(size_t)(e2 & 0xffffu) * (W4) + (j)];                 \
            uint2 t3 = T2[(size_t)(e3 & 0xffffu) * (W4) + (j)];                 \
            uint2 t4 = T2[(size_t)(e4 & 0xffffu) * (W4) + (j)];                 \
            uint2 t5 = T2[(size_t)(e5 & 0xffffu) * (W4) + (j)];                 \
            uint2 t6 = T2[(size_t)(e6 & 0xffffu) * (W4) + (j)];                 \
            uint2 t7 = T2[(size_t)(e7 & 0xffffu) * (W4) + (j)];                 \
            AGG_ACC(t0, w0) AGG_ACC(t1, w1) AGG_ACC(t2, w2) AGG_ACC(t3, w3)     \
            AGG_ACC(t4, w4) AGG_ACC(t5, w5) AGG_ACC(t6, w6) AGG_ACC(t7, w7)     \
        }                                                                       \
    }

#define AGG_ACC(tv, wv)                                   \
        acc.x += wv * BL(tv.x);                           \
        acc.y += wv * BH(tv.x);                           \
        acc.z += wv * BL(tv.y);                           \
        acc.w += wv * BH(tv.y);

// uint4 variant: 16B/lane gathers, 8 bf16 dims per lane (a0,a1 in scope)

#define AGG_ACC4(tv, wv)                                  \
        a0.x += wv * BL(tv.x); a0.y += wv * BH(tv.x);     \
        a0.z += wv * BL(tv.y); a0.w += wv * BH(tv.y);     \
        a1.x += wv * BL(tv.z); a1.y += wv * BH(tv.z);     \
        a1.z += wv * BL(tv.w); a1.w += wv * BH(tv.w);

#define AGG_BODY4(T4, W4, g, j)                                                 \
    {                                                                           \
        int lo = row_ptr[g], hi = row_ptr[(g) + 1];                             \
        for (int k = lo; k < hi; k += 8) {                                      \
            unsigned e0 = csr_ew[min(k + 0, hi - 1)];                           \
            unsigned e1 = csr_ew[min(k + 1, hi - 1)];                           \
            unsigned e2 = csr_ew[min(k + 2, hi - 1)];                           \
            unsigned e3 = csr_ew[min(k + 3, hi - 1)];                           \
            unsigned e4 = csr_ew[min(k + 4, hi - 1)];                           \
            unsigned e5 = csr_ew[min(k + 5, hi - 1)];                           \
            unsigned e6 = csr_ew[min(k + 6, hi - 1)];                           \
            unsigned e7 = csr_ew[min(k + 7, hi - 1)];                           \
            float w0 = __half2float(__ushort_as_half((unsigned short)(e0 >> 16)));                     \
            float w1 = (k + 1 < hi) ? __half2float(__ushort_as_half((unsigned short)(e1 >> 16))) : 0.0f;\
            float w2 = (k + 2 < hi) ? __half2float(__ushort_as_half((unsigned short)(e2 >> 16))) : 0.0f;\
            float w3 = (k + 3 < hi) ? __half2float(__ushort_as_half((unsigned short)(e3 >> 16))) : 0.0f;\
            float w4 = (k + 4 < hi) ? __half2float(__ushort_as_half((unsigned short)(e4 >> 16))) : 0.0f;\
            float w5 = (k + 5 < hi) ? __half2float(__ushort_as_half((unsigned short)(e5 >> 16))) : 0.0f;\
            float w6 = (k + 6 < hi) ? __half2float(__ushort_as_half((unsigned short)(e6 >> 16))) : 0.0f;\
            float w7 = (k + 7 < hi) ? __half2float(__ushort_as_half((unsigned short)(e7 >> 16))) : 0.0f;\
            uint4 t0 = T4[(size_t)(e0 & 0xffffu) * (W4) + (j)];                 \
            uint4 t1 = T4[(size_t)(e1 & 0xffffu) * (W4) + (j)];                 \
            uint4 t2 = T4[(size_t)(e2 & 0xffffu) * (W4) + (j)];                 \
            uint4 t3 = T4[(size_t)(e3 & 0xffffu) * (W4) + (j)];                 \
            uint4 t4 = T4[(size_t)(e4 & 0xffffu) * (W4) + (j)];                 \
            uint4 t5 = T4[(size_t)(e5 & 0xffffu) * (W4) + (j)];                 \
            uint4 t6 = T4[(size_t)(e6 & 0xffffu) * (W4) + (j)];                 \
            uint4 t7 = T4[(size_t)(e7 & 0xffffu) * (W4) + (j)];                 \
            AGG_ACC4(t0, w0) AGG_ACC4(t1, w1) AGG_ACC4(t2, w2) AGG_ACC4(t3, w3) \
            AGG_ACC4(t4, w4) AGG_ACC4(t5, w5) AGG_ACC4(t6, w6) AGG_ACC4(t7, w7) \
        }                                                                       \
    }

// ---------------- agg1 (x bf16, W4=11) -> bf16 out (linear, coalesced) ----------------

__global__ void k_agg1(const unsigned* __restrict__ T, const float* __restrict__ dinv,
                       const int* __restrict__ row_ptr, const unsigned* __restrict__ csr_ew,
                       unsigned short* __restrict__ O, int n) {
    int idx = blockIdx.x * 256 + threadIdx.x;
    if (idx >= n * 11) return;
    int g = idx / 11;
    int j = idx - g * 11;

    const uint2* T2 = (const uint2*)T;
    float di = dinv[g];
    float sw = di * di;
    uint2 sv = T2[(size_t)g * 11 + j];
    float4 acc;
    acc.x = sw * BL(sv.x);
    acc.y = sw * BH(sv.x);
    acc.z = sw * BL(sv.y);
    acc.w = sw * BH(sv.y);
    AGG_BODY(T2, 11, g, j, acc)
    uint2 o;
    o.x = pack_bf2(acc.x, acc.y);
    o.y = pack_bf2(acc.z, acc.w);
    ((uint2*)O)[(size_t)g * 11 + j] = o;
}

// ---------------- register-blocked GEMM, wave-uniform (scalar) W loads ----------------

template<int DI, int DO, int CT, bool BIAS_RELU, bool IN_BF16, bool OUT_BF16>
__global__ void k_gemm(const void* __restrict__ Xv, const float* __restrict__ W,
                       const float* __restrict__ b, void* __restrict__ H, int n) {
    const int ct0 = blockIdx.y * CT;
    int node = blockIdx.x * blockDim.x + threadIdx.x;
    if (node >= n) return;

    float acc[CT];
    #pragma unroll
    for (int c = 0; c < CT; ++c) acc[c] = BIAS_RELU ? b[ct0 + c] : 0.0f;

    const float* Wb = W + ct0;
    #pragma unroll
    for (int k0 = 0; k0 < DI / 4; ++k0) {
        float x0, x1, x2, x3;
        if (IN_BF16) {
            uint2 xv = ((const uint2*)((const unsigned short*)Xv + (size_t)node * DI))[k0];
            x0 = BL(xv.x); x1 = BH(xv.x); x2 = BL(xv.y); x3 = BH(xv.y);
        } else {
            float4 xv = ((const float4*)((const float*)Xv + (size_t)node * DI))[k0];
            x0 = xv.x; x1 = xv.y; x2 = xv.z; x3 = xv.w;
        }
        #pragma unroll
        for (int c = 0; c < CT; ++c) acc[c] += x0 * Wb[(k0 * 4 + 0) * DO + c];
        #pragma unroll
        for (int c = 0; c < CT; ++c) acc[c] += x1 * Wb[(k0 * 4 + 1) * DO + c];
        #pragma unroll
        for (int c = 0; c < CT; ++c) acc[c] += x2 * Wb[(k0 * 4 + 2) * DO + c];
        #pragma unroll
        for (int c = 0; c < CT; ++c) acc[c] += x3 * Wb[(k0 * 4 + 3) * DO + c];
    }

    #pragma unroll
    for (int c4 = 0; c4 < CT / 4; ++c4) {
        float4 v;
        v.x = acc[c4 * 4 + 0]; v.y = acc[c4 * 4 + 1];
        v.z = acc[c4 * 4 + 2]; v.w = acc[c4 * 4 + 3];
        if (BIAS_RELU) {
            v.x = fmaxf(v.x, 0.0f); v.y = fmaxf(v.y, 0.0f);
            v.z = fmaxf(v.z, 0.0f); v.w = fmaxf(v.w, 0.0f);
        }
        if (OUT_BF16) {
            uint2 p;
            p.x = pack_bf2(v.x, v.y);
            p.y = pack_bf2(v.z, v.w);
            ((uint2*)((unsigned short*)H + (size_t)node * DO + ct0))[c4] = p;
        } else {
            ((float4*)((float*)H + (size_t)node * DO + ct0))[c4] = v;
        }
    }
}

// ---------------- fused agg2+gemm3 ----------------
// 256 threads = 4 waves; 8 lanes/node x uint4 (16B) gathers; 32 nodes/block.
// (was 64-thread workgroups: 1-wave wgs cap residency at ~16 waves/CU via the
//  16-wg/CU limit -- too few to hide the 2 dependent L2 rounds per 8-edge iter)

__global__ void __launch_bounds__(256) k_fused23(
        const unsigned* __restrict__ T, const float* __restrict__ dinv,
        const int* __restrict__ row_ptr, const unsigned* __restrict__ csr_ew,
        const float* __restrict__ b2, const float* __restrict__ W3,
        unsigned short* __restrict__ outH, int n) {
    __shared__ float Xs[32 * 68];    // 64 + 4 pad (16B-aligned rows, 2-way banks max)
    const int t = threadIdx.x;
    const int m = t >> 3;            // node slot 0..31
    const int j = t & 7;             // 8 lanes/node, 8 bf16 dims each
    const int g = blockIdx.x * 32 + m;
    const int gm = min(g, n - 1);

    const uint4* T4 = (const uint4*)T;
    {
        float di = dinv[gm];
        float sw = di * di;
        uint4 sv = T4[(size_t)gm * 8 + j];
        float4 a0, a1;
        a0.x = sw * BL(sv.x); a0.y = sw * BH(sv.x);
        a0.z = sw * BL(sv.y); a0.w = sw * BH(sv.y);
        a1.x = sw * BL(sv.z); a1.y = sw * BH(sv.z);
        a1.z = sw * BL(sv.w); a1.w = sw * BH(sv.w);
        AGG_BODY4(T4, 8, gm, j)
        float4 bv0 = ((const float4*)b2)[2 * j];
        float4 bv1 = ((const float4*)b2)[2 * j + 1];
        a0.x = fmaxf(a0.x + bv0.x, 0.0f); a0.y = fmaxf(a0.y + bv0.y, 0.0f);
        a0.z = fmaxf(a0.z + bv0.z, 0.0f); a0.w = fmaxf(a0.w + bv0.w, 0.0f);
        a1.x = fmaxf(a1.x + bv1.x, 0.0f); a1.y = fmaxf(a1.y + bv1.y, 0.0f);
        a1.z = fmaxf(a1.z + bv1.z, 0.0f); a1.w = fmaxf(a1.w + bv1.w, 0.0f);
        *(float4*)&Xs[m * 68 + 8 * j]     = a0;
        *(float4*)&Xs[m * 68 + 8 * j + 4] = a1;
    }
    __syncthreads();

    // gemm3: lane computes cols c = 4j..4j+3 of node m
    {
        const int c = j * 4;
        float4 o = {0.0f, 0.0f, 0.0f, 0.0f};
        #pragma unroll 4
        for (int k4 = 0; k4 < 16; ++k4) {
            float4 xs = *(const float4*)&Xs[m * 68 + 4 * k4];
#define G3(hs, kk) { float4 wv = *(const float4*)&W3[(kk) * 32 + c];            \
            o.x += (hs) * wv.x; o.y += (hs) * wv.y;                             \
            o.z += (hs) * wv.z; o.w += (hs) * wv.w; }
            G3(xs.x, 4 * k4 + 0) G3(xs.y, 4 * k4 + 1)
            G3(xs.z, 4 * k4 + 2) G3(xs.w, 4 * k4 + 3)
#undef G3
        }
        if (g < n) {
            uint2 ov;
            ov.x = pack_bf2(o.x, o.y);
            ov.y = pack_bf2(o.z, o.w);
            *(uint2*)(outH + (size_t)g * 32 + c) = ov;
        }
    }
}

// ---------------- fused agg3+MLP head ----------------
// 128 threads = 2 waves; 4 lanes/node x uint4 gathers; 32 nodes/block.

__global__ void __launch_bounds__(128) k_fused3m(
        const unsigned* __restrict__ T, const float* __restrict__ dinv,
        const int* __restrict__ row_ptr, const unsigned* __restrict__ csr_ew,
        const float* __restrict__ b3,
        const float* __restrict__ Wf1, const float* __restrict__ bf1,
        const float* __restrict__ Wf2, const float* __restrict__ bf2,
        float* __restrict__ out, int n) {
    __shared__ float Xs[32 * 36];    // 32 + 4 pad
    const int t = threadIdx.x;
    const int m = t >> 2;            // node slot 0..31
    const int j = t & 3;             // 4 lanes/node, 8 bf16 dims each
    const int g = blockIdx.x * 32 + m;
    const int gm = min(g, n - 1);

    const uint4* T4 = (const uint4*)T;
    {
        float di = dinv[gm];
        float sw = di * di;
        uint4 sv = T4[(size_t)gm * 4 + j];
        float4 a0, a1;
        a0.x = sw * BL(sv.x); a0.y = sw * BH(sv.x);
        a0.z = sw * BL(sv.y); a0.w = sw * BH(sv.y);
        a1.x = sw * BL(sv.z); a1.y = sw * BH(sv.z);
        a1.z = sw * BL(sv.w); a1.w = sw * BH(sv.w);
        AGG_BODY4(T4, 4, gm, j)
        float4 bv0 = ((const float4*)b3)[2 * j];
        float4 bv1 = ((const float4*)b3)[2 * j + 1];
        a0.x = fmaxf(a0.x + bv0.x, 0.0f); a0.y = fmaxf(a0.y + bv0.y, 0.0f);
        a0.z = fmaxf(a0.z + bv0.z, 0.0f); a0.w = fmaxf(a0.w + bv0.w, 0.0f);
        a1.x = fmaxf(a1.x + bv1.x, 0.0f); a1.y = fmaxf(a1.y + bv1.y, 0.0f);
        a1.z = fmaxf(a1.z + bv1.z, 0.0f); a1.w = fmaxf(a1.w + bv1.w, 0.0f);
        *(float4*)&Xs[m * 36 + 8 * j]     = a0;
        *(float4*)&Xs[m * 36 + 8 * j + 4] = a1;
    }
    __syncthreads();

    // MLP: lane j computes hidden cols 4j..4j+3; shuffle-reduce 4 lanes
    {
        const int c = j * 4;
        float4 h = *(const float4*)&bf1[c];
        #pragma unroll
        for (int k4 = 0; k4 < 8; ++k4) {
            float4 xs = *(const float4*)&Xs[m * 36 + 4 * k4];
#define FM(hs, kk) { float4 wv = *(const float4*)&Wf1[(kk) * 16 + c];           \
            h.x += (hs) * wv.x; h.y += (hs) * wv.y;                             \
            h.z += (hs) * wv.z; h.w += (hs) * wv.w; }
            FM(xs.x, 4 * k4 + 0) FM(xs.y, 4 * k4 + 1)
            FM(xs.z, 4 * k4 + 2) FM(xs.w, 4 * k4 + 3)
#undef FM
        }
        float4 w2 = *(const float4*)&Wf2[c];
        float p = fmaxf(h.x, 0.0f) * w2.x + fmaxf(h.y, 0.0f) * w2.y
                + fmaxf(h.z, 0.0f) * w2.z + fmaxf(h.w, 0.0f) * w2.w;
        p += __shfl_down(p, 2);
        p += __shfl_down(p, 1);
        if (j == 0 && g < n) out[g] = 1.0f / (1.0f + expf(-(p + bf2[0])));
    }
}

// ---------------- launch ----------------

extern "C" void kernel_launch(void* const* d_in, const int* in_sizes, int n_in,
                              void* d_out, int out_size, void* d_ws, size_t ws_size,
                              hipStream_t stream) {
    const float* x   = (const float*)d_in[0];
    const int*   ei  = (const int*)d_in[1];
    const float* W1  = (const float*)d_in[2];
    const float* b1  = (const float*)d_in[3];
    const float* W2  = (const float*)d_in[4];
    const float* b2  = (const float*)d_in[5];
    const float* W3  = (const float*)d_in[6];
    const float* b3  = (const float*)d_in[7];
    const float* Wf1 = (const float*)d_in[8];
    const float* bf1 = (const float*)d_in[9];
    const float* Wf2 = (const float*)d_in[10];
    const float* bf2 = (const float*)d_in[11];
    float* out = (float*)d_out;

    const int N = N_NODES, E = N_EDGES;
    const int* src = ei;
    const int* dst = ei + E;

    const int B   = 256;
    const int NB  = (N + B - 1) / B;        // 196
    const int NBX = 200;                    // multiple of 8 (XCD count)

    char* w = (char*)d_ws;
    float*    dinv    = (float*)w;     w += (size_t)N * 4;
    int*      degc    = (int*)w;       w += (size_t)N * 4;
    int*      row_ptr = (int*)w;       w += (size_t)(N + 4) * 4;
    int*      cursor  = (int*)w;       w += (size_t)N * 4;
    int*      bsum    = (int*)w;       w += (size_t)256 * 4;
    unsigned* csr_ew  = (unsigned*)w;  w += (size_t)E * 4;
    unsigned* xh      = (unsigned*)w;  w += (size_t)N * 44 * 2;   // x bf16
    unsigned short* aggXh = (unsigned short*)w;  w += (size_t)N * 44 * 2;   // agg1 out bf16
    float*    buf1    = (float*)w;     w += (size_t)N * 128 * 4;  // h1 fp32
    unsigned short* bufAh = (unsigned short*)w;  w += (size_t)N * 64 * 2;   // t2 bf16
    unsigned short* bufBh = (unsigned short*)w;  w += (size_t)N * 32 * 2;   // t3 bf16

    // ---- CSR build + x packing (10 dispatches total, was 12) ----
    k_packx    <<<(N * 22 + B - 1) / B, B, 0, stream>>>(x, xh, N * 22, degc, N);
    k_count    <<<(E + B - 1) / B, B, 0, stream>>>(dst, degc, E);
    k_blocksum <<<NB, B, 0, stream>>>(degc, bsum, N);
    k_rowptr   <<<NB, B, 0, stream>>>(degc, bsum, row_ptr, cursor, dinv, N, NB);
    k_fill     <<<(E + B - 1) / B, B, 0, stream>>>(src, dst, dinv, cursor, csr_ew, E);

    // ---- layer 1 ----
    k_agg1<<<(N * 11 + B - 1) / B, B, 0, stream>>>(xh, dinv, row_ptr, csr_ew, aggXh, N);
    k_gemm<44, 128, 16, true, true, false><<<dim3(NBX, 8), B, 0, stream>>>(aggXh, W1, b1, buf1, N);
    k_gemm<128, 64, 16, false, false, true><<<dim3(NBX, 4), B, 0, stream>>>(buf1, W2, nullptr, bufAh, N);

    // ---- layer 2+3: fused agg2+gemm3 -> t3 (bf16) ----
    k_fused23<<<(N + 31) / 32, 256, 0, stream>>>((const unsigned*)bufAh, dinv, row_ptr,
                                                 csr_ew, b2, W3, bufBh, N);

    // ---- layer 3 agg + MLP head ----
    k_fused3m<<<(N + 31) / 32, 128, 0, stream>>>((const unsigned*)bufBh, dinv, row_ptr,
                                                 csr_ew, b3, Wf1, bf1, Wf2, bf2, out, N);
}

// Round 2
// 244.719 us; speedup vs baseline: 1.0753x; 1.0079x over previous
//
#include <hip/hip_runtime.h>
#include <hip/hip_bf16.h>
#include <hip/hip_fp16.h>
#include <math.h>

#define N_NODES 50000
#define N_EDGES 600000
#define D_IN    44

// ---------------- bf16 helpers (bit ops, RNE pack) ----------------

__device__ __forceinline__ unsigned pack_bf2(float a, float b) {
    unsigned ua = __float_as_uint(a);
    ua = (ua + 0x7fffu + ((ua >> 16) & 1u)) >> 16;
    unsigned ub = __float_as_uint(b);
    ub = (ub + 0x7fffu + ((ub >> 16) & 1u)) & 0xffff0000u;
    return ua | ub;
}

#define BL(u) __uint_as_float((u) << 16)
#define BH(u) __uint_as_float((u) & 0xffff0000u)

// ---------------- CSR build ----------------

// packx also zeroes degc (merged k_zero: N << N*22 so grid covers both)
__global__ void k_packx(const float* __restrict__ x, unsigned* __restrict__ xh,
                        int npairs, int* __restrict__ degc, int n) {
    int i = blockIdx.x * blockDim.x + threadIdx.x;
    if (i < npairs) {
        float2 v = ((const float2*)x)[i];
        xh[i] = pack_bf2(v.x, v.y);
    }
    if (i < n) degc[i] = 0;
}

__global__ void k_count(const int* __restrict__ dst, int* degc, int e) {
    int i = blockIdx.x * blockDim.x + threadIdx.x;
    if (i < e) atomicAdd(&degc[dst[i]], 1);
}

__global__ void k_blocksum(const int* __restrict__ degc, int* __restrict__ bsum, int n) {
    int i = blockIdx.x * 256 + threadIdx.x;
    int v = (i < n) ? degc[i] : 0;
    #pragma unroll
    for (int off = 32; off > 0; off >>= 1) v += __shfl_down(v, off, 64);
    __shared__ int ws[4];
    if ((threadIdx.x & 63) == 0) ws[threadIdx.x >> 6] = v;
    __syncthreads();
    if (threadIdx.x == 0) bsum[blockIdx.x] = ws[0] + ws[1] + ws[2] + ws[3];
}

// rowptr re-scans bsum locally per block (nb<=256; redundant scan is cheaper
// than a separate launch)
__global__ void k_rowptr(const int* __restrict__ degc, const int* __restrict__ bsum,
                         int* __restrict__ row_ptr, int* __restrict__ cursor,
                         float* __restrict__ dinv, int n, int nb) {
    __shared__ int sb[256];
    __shared__ int s[256];
    int t = threadIdx.x;

    int bv = (t < nb) ? bsum[t] : 0;
    sb[t] = bv;
    __syncthreads();
    #pragma unroll
    for (int off = 1; off < 256; off <<= 1) {
        int u = (t >= off) ? sb[t - off] : 0;
        __syncthreads();
        sb[t] += u;
        __syncthreads();
    }
    int prefix = (blockIdx.x == 0) ? 0 : sb[blockIdx.x - 1];

    int i = blockIdx.x * 256 + t;
    int d = (i < n) ? degc[i] : 0;
    s[t] = d;
    __syncthreads();
    #pragma unroll
    for (int off = 1; off < 256; off <<= 1) {
        int u = (t >= off) ? s[t - off] : 0;
        __syncthreads();
        s[t] += u;
        __syncthreads();
    }
    int ex = s[t] - d + prefix;
    if (i < n) {
        row_ptr[i] = ex;
        cursor[i]  = ex;
        dinv[i]    = rsqrtf(1.0f + (float)d);
        if (i == n - 1) row_ptr[n] = ex + d;
    }
}

// 4-byte CSR entry: src (16 bits, N<65536) | fp16 weight << 16
__global__ void k_fill(const int* __restrict__ src, const int* __restrict__ dst,
                       const float* __restrict__ dinv, int* cursor,
                       unsigned* __restrict__ csr_ew, int e) {
    int i = blockIdx.x * blockDim.x + threadIdx.x;
    if (i < e) {
        int s = src[i], d = dst[i];
        int p = atomicAdd(&cursor[d], 1);
        __half h = __float2half(dinv[s] * dinv[d]);
        csr_ew[p] = (unsigned)s | ((unsigned)__half_as_ushort(h) << 16);
    }
}

// ---------------- 8-deep predicated bf16 gather macros ----------------
// EW = edge array (LDS-staged or global fallback); lo/hi local offsets.

#define AGG_EDGE_HDR(EW, lo, hi)                                                \
            unsigned e0 = EW[min(k + 0, (hi) - 1)];                             \
            unsigned e1 = EW[min(k + 1, (hi) - 1)];                             \
            unsigned e2 = EW[min(k + 2, (hi) - 1)];                             \
            unsigned e3 = EW[min(k + 3, (hi) - 1)];                             \
            unsigned e4 = EW[min(k + 4, (hi) - 1)];                             \
            unsigned e5 = EW[min(k + 5, (hi) - 1)];                             \
            unsigned e6 = EW[min(k + 6, (hi) - 1)];                             \
            unsigned e7 = EW[min(k + 7, (hi) - 1)];                             \
            float w0 = __half2float(__ushort_as_half((unsigned short)(e0 >> 16)));                     \
            float w1 = (k + 1 < (hi)) ? __half2float(__ushort_as_half((unsigned short)(e1 >> 16))) : 0.0f;\
            float w2 = (k + 2 < (hi)) ? __half2float(__ushort_as_half((unsigned short)(e2 >> 16))) : 0.0f;\
            float w3 = (k + 3 < (hi)) ? __half2float(__ushort_as_half((unsigned short)(e3 >> 16))) : 0.0f;\
            float w4 = (k + 4 < (hi)) ? __half2float(__ushort_as_half((unsigned short)(e4 >> 16))) : 0.0f;\
            float w5 = (k + 5 < (hi)) ? __half2float(__ushort_as_half((unsigned short)(e5 >> 16))) : 0.0f;\
            float w6 = (k + 6 < (hi)) ? __half2float(__ushort_as_half((unsigned short)(e6 >> 16))) : 0.0f;\
            float w7 = (k + 7 < (hi)) ? __half2float(__ushort_as_half((unsigned short)(e7 >> 16))) : 0.0f;

// uint2 variant (k_agg1, 44-dim rows = 11 x 8B)

#define AGG_ACC(tv, wv)                                   \
        acc.x += wv * BL(tv.x);                           \
        acc.y += wv * BH(tv.x);                           \
        acc.z += wv * BL(tv.y);                           \
        acc.w += wv * BH(tv.y);

#define AGG_BODY(T2, W4, lo, hi, j, acc, EW)                                    \
    {                                                                           \
        for (int k = (lo); k < (hi); k += 8) {                                  \
            AGG_EDGE_HDR(EW, lo, hi)                                            \
            uint2 t0 = T2[(size_t)(e0 & 0xffffu) * (W4) + (j)];                 \
            uint2 t1 = T2[(size_t)(e1 & 0xffffu) * (W4) + (j)];                 \
            uint2 t2 = T2[(size_t)(e2 & 0xffffu) * (W4) + (j)];                 \
            uint2 t3 = T2[(size_t)(e3 & 0xffffu) * (W4) + (j)];                 \
            uint2 t4 = T2[(size_t)(e4 & 0xffffu) * (W4) + (j)];                 \
            uint2 t5 = T2[(size_t)(e5 & 0xffffu) * (W4) + (j)];                 \
            uint2 t6 = T2[(size_t)(e6 & 0xffffu) * (W4) + (j)];                 \
            uint2 t7 = T2[(size_t)(e7 & 0xffffu) * (W4) + (j)];                 \
            AGG_ACC(t0, w0) AGG_ACC(t1, w1) AGG_ACC(t2, w2) AGG_ACC(t3, w3)     \
            AGG_ACC(t4, w4) AGG_ACC(t5, w5) AGG_ACC(t6, w6) AGG_ACC(t7, w7)     \
        }                                                                       \
    }

// uint4 variant: 16B/lane gathers, 8 bf16 dims per lane (a0,a1 in scope)

#define AGG_ACC4(tv, wv)                                  \
        a0.x += wv * BL(tv.x); a0.y += wv * BH(tv.x);     \
        a0.z += wv * BL(tv.y); a0.w += wv * BH(tv.y);     \
        a1.x += wv * BL(tv.z); a1.y += wv * BH(tv.z);     \
        a1.z += wv * BL(tv.w); a1.w += wv * BH(tv.w);

#define AGG_BODY4(T4, W4, lo, hi, j, EW)                                        \
    {                                                                           \
        for (int k = (lo); k < (hi); k += 8) {                                  \
            AGG_EDGE_HDR(EW, lo, hi)                                            \
            uint4 t0 = T4[(size_t)(e0 & 0xffffu) * (W4) + (j)];                 \
            uint4 t1 = T4[(size_t)(e1 & 0xffffu) * (W4) + (j)];                 \
            uint4 t2 = T4[(size_t)(e2 & 0xffffu) * (W4) + (j)];                 \
            uint4 t3 = T4[(size_t)(e3 & 0xffffu) * (W4) + (j)];                 \
            uint4 t4 = T4[(size_t)(e4 & 0xffffu) * (W4) + (j)];                 \
            uint4 t5 = T4[(size_t)(e5 & 0xffffu) * (W4) + (j)];                 \
            uint4 t6 = T4[(size_t)(e6 & 0xffffu) * (W4) + (j)];                 \
            uint4 t7 = T4[(size_t)(e7 & 0xffffu) * (W4) + (j)];                 \
            AGG_ACC4(t0, w0) AGG_ACC4(t1, w1) AGG_ACC4(t2, w2) AGG_ACC4(t3, w3) \
            AGG_ACC4(t4, w4) AGG_ACC4(t5, w5) AGG_ACC4(t6, w6) AGG_ACC4(t7, w7) \
        }                                                                       \
    }

// ---------------- agg1 (x bf16, W4=11) -> bf16 out ----------------
// Block stages its contiguous csr range into LDS once (coalesced); the
// per-lane edge reads become LDS broadcasts instead of redundant L2 loads.

#define AGG1_ECAP 1536

__global__ void k_agg1(const unsigned* __restrict__ T, const float* __restrict__ dinv,
                       const int* __restrict__ row_ptr, const unsigned* __restrict__ csr_ew,
                       unsigned short* __restrict__ O, int n) {
    __shared__ unsigned csr_s[AGG1_ECAP];
    const int t = threadIdx.x;
    const int base = blockIdx.x * 256;
    const int g0 = base / 11;
    const int glast = min((base + 255) / 11, n - 1);
    const int lo_blk = row_ptr[g0];
    const int nume = row_ptr[glast + 1] - lo_blk;
    const unsigned* ep;
    if (nume <= AGG1_ECAP) {
        for (int i = t; i < nume; i += 256) csr_s[i] = csr_ew[lo_blk + i];
        ep = csr_s;
    } else {
        ep = csr_ew + lo_blk;    // fallback (never for this graph size)
    }
    __syncthreads();

    int idx = base + t;
    if (idx >= n * 11) return;
    int g = idx / 11;
    int j = idx - g * 11;

    const uint2* T2 = (const uint2*)T;
    float di = dinv[g];
    float sw = di * di;
    uint2 sv = T2[(size_t)g * 11 + j];
    float4 acc;
    acc.x = sw * BL(sv.x);
    acc.y = sw * BH(sv.x);
    acc.z = sw * BL(sv.y);
    acc.w = sw * BH(sv.y);
    int lo = row_ptr[g] - lo_blk;
    int hi = row_ptr[g + 1] - lo_blk;
    AGG_BODY(T2, 11, lo, hi, j, acc, ep)
    uint2 o;
    o.x = pack_bf2(acc.x, acc.y);
    o.y = pack_bf2(acc.z, acc.w);
    ((uint2*)O)[(size_t)g * 11 + j] = o;
}

// ---------------- register-blocked GEMM, wave-uniform (scalar) W loads ----------------

template<int DI, int DO, int CT, bool BIAS_RELU, bool IN_BF16, bool OUT_BF16>
__global__ void k_gemm(const void* __restrict__ Xv, const float* __restrict__ W,
                       const float* __restrict__ b, void* __restrict__ H, int n) {
    const int ct0 = blockIdx.y * CT;
    int node = blockIdx.x * blockDim.x + threadIdx.x;
    if (node >= n) return;

    float acc[CT];
    #pragma unroll
    for (int c = 0; c < CT; ++c) acc[c] = BIAS_RELU ? b[ct0 + c] : 0.0f;

    const float* Wb = W + ct0;
    #pragma unroll
    for (int k0 = 0; k0 < DI / 4; ++k0) {
        float x0, x1, x2, x3;
        if (IN_BF16) {
            uint2 xv = ((const uint2*)((const unsigned short*)Xv + (size_t)node * DI))[k0];
            x0 = BL(xv.x); x1 = BH(xv.x); x2 = BL(xv.y); x3 = BH(xv.y);
        } else {
            float4 xv = ((const float4*)((const float*)Xv + (size_t)node * DI))[k0];
            x0 = xv.x; x1 = xv.y; x2 = xv.z; x3 = xv.w;
        }
        #pragma unroll
        for (int c = 0; c < CT; ++c) acc[c] += x0 * Wb[(k0 * 4 + 0) * DO + c];
        #pragma unroll
        for (int c = 0; c < CT; ++c) acc[c] += x1 * Wb[(k0 * 4 + 1) * DO + c];
        #pragma unroll
        for (int c = 0; c < CT; ++c) acc[c] += x2 * Wb[(k0 * 4 + 2) * DO + c];
        #pragma unroll
        for (int c = 0; c < CT; ++c) acc[c] += x3 * Wb[(k0 * 4 + 3) * DO + c];
    }

    #pragma unroll
    for (int c4 = 0; c4 < CT / 4; ++c4) {
        float4 v;
        v.x = acc[c4 * 4 + 0]; v.y = acc[c4 * 4 + 1];
        v.z = acc[c4 * 4 + 2]; v.w = acc[c4 * 4 + 3];
        if (BIAS_RELU) {
            v.x = fmaxf(v.x, 0.0f); v.y = fmaxf(v.y, 0.0f);
            v.z = fmaxf(v.z, 0.0f); v.w = fmaxf(v.w, 0.0f);
        }
        if (OUT_BF16) {
            uint2 p;
            p.x = pack_bf2(v.x, v.y);
            p.y = pack_bf2(v.z, v.w);
            ((uint2*)((unsigned short*)H + (size_t)node * DO + ct0))[c4] = p;
        } else {
            ((float4*)((float*)H + (size_t)node * DO + ct0))[c4] = v;
        }
    }
}

// ---------------- fused agg2+gemm3 ----------------
// 256 threads = 4 waves; 8 lanes/node x uint4 gathers; 32 nodes/block.
// csr range LDS-staged (coalesced) -> edge reads are LDS broadcasts.

#define F23_ECAP 2048

__global__ void __launch_bounds__(256) k_fused23(
        const unsigned* __restrict__ T, const float* __restrict__ dinv,
        const int* __restrict__ row_ptr, const unsigned* __restrict__ csr_ew,
        const float* __restrict__ b2, const float* __restrict__ W3,
        unsigned short* __restrict__ outH, int n) {
    __shared__ unsigned csr_s[F23_ECAP];
    __shared__ float Xs[32 * 68];    // 64 + 4 pad
    const int t = threadIdx.x;
    const int m = t >> 3;            // node slot 0..31
    const int j = t & 7;             // 8 lanes/node, 8 bf16 dims each
    const int g = blockIdx.x * 32 + m;
    const int gm = min(g, n - 1);

    const int g0 = blockIdx.x * 32;
    const int glast = min(g0 + 31, n - 1);
    const int lo_blk = row_ptr[g0];
    const int nume = row_ptr[glast + 1] - lo_blk;
    const unsigned* ep;
    if (nume <= F23_ECAP) {
        for (int i = t; i < nume; i += 256) csr_s[i] = csr_ew[lo_blk + i];
        ep = csr_s;
    } else {
        ep = csr_ew + lo_blk;
    }
    __syncthreads();

    const uint4* T4 = (const uint4*)T;
    {
        float di = dinv[gm];
        float sw = di * di;
        uint4 sv = T4[(size_t)gm * 8 + j];
        float4 a0, a1;
        a0.x = sw * BL(sv.x); a0.y = sw * BH(sv.x);
        a0.z = sw * BL(sv.y); a0.w = sw * BH(sv.y);
        a1.x = sw * BL(sv.z); a1.y = sw * BH(sv.z);
        a1.z = sw * BL(sv.w); a1.w = sw * BH(sv.w);
        int lo = row_ptr[gm] - lo_blk;
        int hi = row_ptr[gm + 1] - lo_blk;
        AGG_BODY4(T4, 8, lo, hi, j, ep)
        float4 bv0 = ((const float4*)b2)[2 * j];
        float4 bv1 = ((const float4*)b2)[2 * j + 1];
        a0.x = fmaxf(a0.x + bv0.x, 0.0f); a0.y = fmaxf(a0.y + bv0.y, 0.0f);
        a0.z = fmaxf(a0.z + bv0.z, 0.0f); a0.w = fmaxf(a0.w + bv0.w, 0.0f);
        a1.x = fmaxf(a1.x + bv1.x, 0.0f); a1.y = fmaxf(a1.y + bv1.y, 0.0f);
        a1.z = fmaxf(a1.z + bv1.z, 0.0f); a1.w = fmaxf(a1.w + bv1.w, 0.0f);
        *(float4*)&Xs[m * 68 + 8 * j]     = a0;
        *(float4*)&Xs[m * 68 + 8 * j + 4] = a1;
    }
    __syncthreads();

    // gemm3: lane computes cols c = 4j..4j+3 of node m
    {
        const int c = j * 4;
        float4 o = {0.0f, 0.0f, 0.0f, 0.0f};
        #pragma unroll 4
        for (int k4 = 0; k4 < 16; ++k4) {
            float4 xs = *(const float4*)&Xs[m * 68 + 4 * k4];
#define G3(hs, kk) { float4 wv = *(const float4*)&W3[(kk) * 32 + c];            \
            o.x += (hs) * wv.x; o.y += (hs) * wv.y;                             \
            o.z += (hs) * wv.z; o.w += (hs) * wv.w; }
            G3(xs.x, 4 * k4 + 0) G3(xs.y, 4 * k4 + 1)
            G3(xs.z, 4 * k4 + 2) G3(xs.w, 4 * k4 + 3)
#undef G3
        }
        if (g < n) {
            uint2 ov;
            ov.x = pack_bf2(o.x, o.y);
            ov.y = pack_bf2(o.z, o.w);
            *(uint2*)(outH + (size_t)g * 32 + c) = ov;
        }
    }
}

// ---------------- fused agg3+MLP head ----------------
// 128 threads = 2 waves; 4 lanes/node x uint4 gathers; 32 nodes/block.

#define F3M_ECAP 2048

__global__ void __launch_bounds__(128) k_fused3m(
        const unsigned* __restrict__ T, const float* __restrict__ dinv,
        const int* __restrict__ row_ptr, const unsigned* __restrict__ csr_ew,
        const float* __restrict__ b3,
        const float* __restrict__ Wf1, const float* __restrict__ bf1,
        const float* __restrict__ Wf2, const float* __restrict__ bf2,
        float* __restrict__ out, int n) {
    __shared__ unsigned csr_s[F3M_ECAP];
    __shared__ float Xs[32 * 36];    // 32 + 4 pad
    const int t = threadIdx.x;
    const int m = t >> 2;            // node slot 0..31
    const int j = t & 3;             // 4 lanes/node, 8 bf16 dims each
    const int g = blockIdx.x * 32 + m;
    const int gm = min(g, n - 1);

    const int g0 = blockIdx.x * 32;
    const int glast = min(g0 + 31, n - 1);
    const int lo_blk = row_ptr[g0];
    const int nume = row_ptr[glast + 1] - lo_blk;
    const unsigned* ep;
    if (nume <= F3M_ECAP) {
        for (int i = t; i < nume; i += 128) csr_s[i] = csr_ew[lo_blk + i];
        ep = csr_s;
    } else {
        ep = csr_ew + lo_blk;
    }
    __syncthreads();

    const uint4* T4 = (const uint4*)T;
    {
        float di = dinv[gm];
        float sw = di * di;
        uint4 sv = T4[(size_t)gm * 4 + j];
        float4 a0, a1;
        a0.x = sw * BL(sv.x); a0.y = sw * BH(sv.x);
        a0.z = sw * BL(sv.y); a0.w = sw * BH(sv.y);
        a1.x = sw * BL(sv.z); a1.y = sw * BH(sv.z);
        a1.z = sw * BL(sv.w); a1.w = sw * BH(sv.w);
        int lo = row_ptr[gm] - lo_blk;
        int hi = row_ptr[gm + 1] - lo_blk;
        AGG_BODY4(T4, 4, lo, hi, j, ep)
        float4 bv0 = ((const float4*)b3)[2 * j];
        float4 bv1 = ((const float4*)b3)[2 * j + 1];
        a0.x = fmaxf(a0.x + bv0.x, 0.0f); a0.y = fmaxf(a0.y + bv0.y, 0.0f);
        a0.z = fmaxf(a0.z + bv0.z, 0.0f); a0.w = fmaxf(a0.w + bv0.w, 0.0f);
        a1.x = fmaxf(a1.x + bv1.x, 0.0f); a1.y = fmaxf(a1.y + bv1.y, 0.0f);
        a1.z = fmaxf(a1.z + bv1.z, 0.0f); a1.w = fmaxf(a1.w + bv1.w, 0.0f);
        *(float4*)&Xs[m * 36 + 8 * j]     = a0;
        *(float4*)&Xs[m * 36 + 8 * j + 4] = a1;
    }
    __syncthreads();

    // MLP: lane j computes hidden cols 4j..4j+3; shuffle-reduce 4 lanes
    {
        const int c = j * 4;
        float4 h = *(const float4*)&bf1[c];
        #pragma unroll
        for (int k4 = 0; k4 < 8; ++k4) {
            float4 xs = *(const float4*)&Xs[m * 36 + 4 * k4];
#define FM(hs, kk) { float4 wv = *(const float4*)&Wf1[(kk) * 16 + c];           \
            h.x += (hs) * wv.x; h.y += (hs) * wv.y;                             \
            h.z += (hs) * wv.z; h.w += (hs) * wv.w; }
            FM(xs.x, 4 * k4 + 0) FM(xs.y, 4 * k4 + 1)
            FM(xs.z, 4 * k4 + 2) FM(xs.w, 4 * k4 + 3)
#undef FM
        }
        float4 w2 = *(const float4*)&Wf2[c];
        float p = fmaxf(h.x, 0.0f) * w2.x + fmaxf(h.y, 0.0f) * w2.y
                + fmaxf(h.z, 0.0f) * w2.z + fmaxf(h.w, 0.0f) * w2.w;
        p += __shfl_down(p, 2);
        p += __shfl_down(p, 1);
        if (j == 0 && g < n) out[g] = 1.0f / (1.0f + expf(-(p + bf2[0])));
    }
}

// ---------------- launch ----------------

extern "C" void kernel_launch(void* const* d_in, const int* in_sizes, int n_in,
                              void* d_out, int out_size, void* d_ws, size_t ws_size,
                              hipStream_t stream) {
    const float* x   = (const float*)d_in[0];
    const int*   ei  = (const int*)d_in[1];
    const float* W1  = (const float*)d_in[2];
    const float* b1  = (const float*)d_in[3];
    const float* W2  = (const float*)d_in[4];
    const float* b2  = (const float*)d_in[5];
    const float* W3  = (const float*)d_in[6];
    const float* b3  = (const float*)d_in[7];
    const float* Wf1 = (const float*)d_in[8];
    const float* bf1 = (const float*)d_in[9];
    const float* Wf2 = (const float*)d_in[10];
    const float* bf2 = (const float*)d_in[11];
    float* out = (float*)d_out;

    const int N = N_NODES, E = N_EDGES;
    const int* src = ei;
    const int* dst = ei + E;

    const int B   = 256;
    const int NB  = (N + B - 1) / B;        // 196
    const int NBX = 200;                    // multiple of 8 (XCD count)

    char* w = (char*)d_ws;
    float*    dinv    = (float*)w;     w += (size_t)N * 4;
    int*      degc    = (int*)w;       w += (size_t)N * 4;
    int*      row_ptr = (int*)w;       w += (size_t)(N + 4) * 4;
    int*      cursor  = (int*)w;       w += (size_t)N * 4;
    int*      bsum    = (int*)w;       w += (size_t)256 * 4;
    unsigned* csr_ew  = (unsigned*)w;  w += (size_t)E * 4;
    unsigned* xh      = (unsigned*)w;  w += (size_t)N * 44 * 2;   // x bf16
    unsigned short* aggXh = (unsigned short*)w;  w += (size_t)N * 44 * 2;   // agg1 out bf16
    float*    buf1    = (float*)w;     w += (size_t)N * 128 * 4;  // h1 fp32
    unsigned short* bufAh = (unsigned short*)w;  w += (size_t)N * 64 * 2;   // t2 bf16
    unsigned short* bufBh = (unsigned short*)w;  w += (size_t)N * 32 * 2;   // t3 bf16

    // ---- CSR build + x packing ----
    k_packx    <<<(N * 22 + B - 1) / B, B, 0, stream>>>(x, xh, N * 22, degc, N);
    k_count    <<<(E + B - 1) / B, B, 0, stream>>>(dst, degc, E);
    k_blocksum <<<NB, B, 0, stream>>>(degc, bsum, N);
    k_rowptr   <<<NB, B, 0, stream>>>(degc, bsum, row_ptr, cursor, dinv, N, NB);
    k_fill     <<<(E + B - 1) / B, B, 0, stream>>>(src, dst, dinv, cursor, csr_ew, E);

    // ---- layer 1 ----
    k_agg1<<<(N * 11 + B - 1) / B, B, 0, stream>>>(xh, dinv, row_ptr, csr_ew, aggXh, N);
    k_gemm<44, 128, 16, true, true, false><<<dim3(NBX, 8), B, 0, stream>>>(aggXh, W1, b1, buf1, N);
    k_gemm<128, 64, 16, false, false, true><<<dim3(NBX, 4), B, 0, stream>>>(buf1, W2, nullptr, bufAh, N);

    // ---- layer 2+3: fused agg2+gemm3 -> t3 (bf16) ----
    k_fused23<<<(N + 31) / 32, 256, 0, stream>>>((const unsigned*)bufAh, dinv, row_ptr,
                                                 csr_ew, b2, W3, bufBh, N);

    // ---- layer 3 agg + MLP head ----
    k_fused3m<<<(N + 31) / 32, 128, 0, stream>>>((const unsigned*)bufBh, dinv, row_ptr,
                                                 csr_ew, b3, Wf1, bf1, Wf2, bf2, out, N);
}